// Round 8
// baseline (341.441 us; speedup 1.0000x reference)
//
#include <hip/hip_runtime.h>
#include <stdint.h>

// ---------- sizes (fixed by setup_inputs) ----------
#define BATCH   65536
#define FIN     32        // layer-1 in
#define HID     64        // layer-1 out / layer-2 in
#define NOUT    2048      // layer-2 out
#define NC      8         // bases per element
#define NF      9         // features per element (silu + 8 bases)
#define K1      288       // FIN*NF
#define K2      576       // HID*NF

// ---------- GEMM2 tiling (m97 structure: 128x128, 4 waves, BK=32, dbuf) ----------
#define BM8     128
#define BN8     128
#define BK8     32
#define KT8     18        // K2 / BK8

typedef __bf16 bf16x8 __attribute__((ext_vector_type(8)));
typedef float f32x4 __attribute__((ext_vector_type(4)));

// ---------- helpers ----------
__device__ __forceinline__ uint16_t f2bf(float f) {
    uint32_t u = __builtin_bit_cast(uint32_t, f);
    uint32_t r = (u + 0x7fffu + ((u >> 16) & 1u)) >> 16;
    return (uint16_t)r;
}
__device__ __forceinline__ float silu_f(float v) {
    return v / (1.f + __expf(-v));
}

// Closed-form uniform cubic B-spline bases. Knots g[t]=(t-3)*0.4-1, t=0..11.
__device__ __forceinline__ void bspline8u(float xv, float out[8]) {
    float s = (xv + 2.2f) * 2.5f;
    int c = (int)floorf(s);
    float gc = (float)(c - 3) * 0.4f - 1.0f;
    float u = (xv - gc) * 2.5f;
    float u1 = 1.f - u;
    float uu = u * u, u3 = uu * u;
    float w0 = u1 * u1 * u1 * (1.f / 6.f);
    float w1 = (3.f * u3 - 6.f * uu + 4.f) * (1.f / 6.f);
    float w2 = (-3.f * u3 + 3.f * uu + 3.f * u + 1.f) * (1.f / 6.f);
    float w3 = u3 * (1.f / 6.f);
#pragma unroll
    for (int t = 0; t < 8; t++) {
        int d = c - t;
        out[t] = (d == 0) ? w3 : (d == 1) ? w2 : (d == 2) ? w1 : (d == 3) ? w0 : 0.f;
    }
}

// ---------- pack kernels ----------
__global__ void pack_w1(const float* __restrict__ bw1, const float* __restrict__ sw1,
                        const float* __restrict__ ss1, uint16_t* __restrict__ w1L) {
    int idx = blockIdx.x * 256 + threadIdx.x;
    if (idx >= 64 * K1) return;
    int o = idx / K1, k = idx % K1;
    int i = k / 9, j = k % 9;
    float v = (j == 0) ? bw1[o * FIN + i]
                       : sw1[(o * FIN + i) * NC + (j - 1)] * ss1[o * FIN + i];
    w1L[idx] = f2bf(v);
}

__global__ void pack_w2(const float* __restrict__ bw2, const float* __restrict__ sw2,
                        const float* __restrict__ ss2, uint16_t* __restrict__ w2p) {
    int idx = blockIdx.x * 256 + threadIdx.x;
    if (idx >= NOUT * K2) return;
    int n = idx / K2, k = idx % K2;
    int j = k >> 6, i = k & 63;
    float v = (j == 0) ? bw2[n * HID + i]
                       : sw2[(n * HID + i) * NC + (j - 1)] * ss2[n * HID + i];
    w2p[idx] = f2bf(v);
}

// ---------- fused LN + featurize1 + MFMA layer1 + featurize2 (r6, verified) ----------
#define FBR    64
#define A1LD   296
#define S2LD   584
__global__ __launch_bounds__(256) void featurize(
    const float* __restrict__ x, const float* __restrict__ lnw, const float* __restrict__ lnb,
    const uint16_t* __restrict__ w1L, uint16_t* __restrict__ a2) {

    __shared__ __align__(16) char fsm[75776];
    uint16_t* w1s = (uint16_t*)fsm;              // [64][296]
    uint16_t* a1s = (uint16_t*)(fsm + 37888);    // [64][296]
    uint16_t* s2  = (uint16_t*)fsm;              // [64][584] (phase 3)

    const int tid = threadIdx.x;
    const int wv = tid >> 6, lane = tid & 63;
    const int rowBase = blockIdx.x * FBR;

#pragma unroll
    for (int t = 0; t < 9; ++t) {
        int idx = t * 256 + tid;
        int o = idx / 36, cc = idx % 36;
        uint4 v = *(const uint4*)(w1L + idx * 8);
        *(uint4*)&w1s[o * A1LD + cc * 8] = v;
    }

    const int prow = tid >> 2, pq = tid & 3;
    const float* xp = x + (size_t)(rowBase + prow) * FIN + pq * 8;
    float xv[8];
    *(float4*)&xv[0] = ((const float4*)xp)[0];
    *(float4*)&xv[4] = ((const float4*)xp)[1];
    float s = 0.f, s2v = 0.f;
#pragma unroll
    for (int j = 0; j < 8; j++) { s += xv[j]; s2v += xv[j] * xv[j]; }
    s += __shfl_xor(s, 1);  s2v += __shfl_xor(s2v, 1);
    s += __shfl_xor(s, 2);  s2v += __shfl_xor(s2v, 2);
    const float mu = s * (1.f / 32.f);
    const float var = s2v * (1.f / 32.f) - mu * mu;
    const float rstd = rsqrtf(var + 1e-5f);

    float wl[8], bl[8];
    *(float4*)&wl[0] = ((const float4*)(lnw + pq * 8))[0];
    *(float4*)&wl[4] = ((const float4*)(lnw + pq * 8))[1];
    *(float4*)&bl[0] = ((const float4*)(lnb + pq * 8))[0];
    *(float4*)&bl[4] = ((const float4*)(lnb + pq * 8))[1];

    __align__(16) uint16_t tmp[72];
#pragma unroll
    for (int ii = 0; ii < 8; ii++) {
        float xn = (xv[ii] - mu) * rstd * wl[ii] + bl[ii];
        tmp[ii * 9] = f2bf(silu_f(xn));
        float bs[8];
        bspline8u(xn, bs);
#pragma unroll
        for (int j = 0; j < 8; j++) tmp[ii * 9 + 1 + j] = f2bf(bs[j]);
    }
    {
        uint16_t* dst = &a1s[prow * A1LD + pq * 72];
#pragma unroll
        for (int q = 0; q < 9; q++) *(uint4*)(dst + q * 8) = *(const uint4*)&tmp[q * 8];
    }
    __syncthreads();

    f32x4 acc[4];
#pragma unroll
    for (int n = 0; n < 4; n++) acc[n] = (f32x4){0.f, 0.f, 0.f, 0.f};
    const int arow = wv * 16 + (lane & 15);
    const int koff = (lane >> 4) * 8;
#pragma unroll
    for (int ks = 0; ks < 9; ++ks) {
        bf16x8 af = *(const bf16x8*)&a1s[arow * A1LD + ks * 32 + koff];
#pragma unroll
        for (int n = 0; n < 4; n++) {
            bf16x8 bv = *(const bf16x8*)&w1s[(n * 16 + (lane & 15)) * A1LD + ks * 32 + koff];
            acc[n] = __builtin_amdgcn_mfma_f32_16x16x32_bf16(af, bv, acc[n], 0, 0, 0);
        }
    }
    __syncthreads();

    const int r0 = wv * 16 + ((lane >> 4) << 2);
    const int cb = lane & 15;
#pragma unroll
    for (int n = 0; n < 4; n++)
#pragma unroll
        for (int r = 0; r < 4; r++) {
            float h = acc[n][r];
            float o9[9];
            o9[0] = silu_f(h);
            bspline8u(h, &o9[1]);
            uint16_t* op = &s2[(size_t)(r0 + r) * S2LD + n * 16 + cb];
#pragma unroll
            for (int j = 0; j < 9; j++) op[j * 64] = f2bf(o9[j]);
        }
    __syncthreads();

#pragma unroll
    for (int q = 0; q < 18; ++q) {
        int g = q * 256 + tid;
        int row = g / 72, c = g % 72;
        uint4 v = *(const uint4*)&s2[row * S2LD + c * 8];
        *(uint4*)(a2 + (size_t)(rowBase + row) * K2 + c * 8) = v;
    }
}

// ---------- GEMM2: (65536 x 576) x (576 x 2048), m97 structure ----------
// A [M][576] bf16 row-major; Bt [N][576] bf16 row-major; C [M][N] fp32.
// 128x128 tile, 4 waves (2x2, wave tile 64x64), BK=32, DOUBLE-buffered LDS
// (32 KiB -> ~3 blocks/CU co-resident: TLP does the pipelining), one
// __syncthreads per K-step, compiler-scheduled waits. Conflict-free XOR
// swizzle (both-sides, rule 21): LDS[row][slot16B] = G[row][slot ^ (row&3)].
__device__ __forceinline__ void gload16(const uint16_t* g, const uint16_t* l) {
    __builtin_amdgcn_global_load_lds(
        (const __attribute__((address_space(1))) void*)g,
        (__attribute__((address_space(3))) void*)l, 16, 0, 0);
}

__global__ __launch_bounds__(256) void gemm2_kernel(const uint16_t* __restrict__ A,
                                                    const uint16_t* __restrict__ Bt,
                                                    float* __restrict__ C) {
    __shared__ __align__(16) uint16_t As[2][BM8 * BK8];   // 2 x 8 KiB
    __shared__ __align__(16) uint16_t Bs[2][BM8 * BK8];   // 2 x 8 KiB

    const int tid = threadIdx.x;
    const int wv = tid >> 6, lane = tid & 63;
    const int wr = wv >> 1, wc = wv & 1;            // 2 x 2 wave grid

    // XCD-chunked swizzle: 8192 blocks, 8 XCDs, chunk 1024; ntile fastest
    // (16 consecutive blocks share one 147 KB A-stripe -> L2 hits).
    const uint32_t bid = blockIdx.x;
    const uint32_t wk = (bid & 7u) * 1024u + (bid >> 3);
    const uint32_t ntile = wk & 15u, mtile = wk >> 4;

    // Staging: thread t -> rows (t>>2) and (t>>2)+64, 16B slot (t&3);
    // LDS dest linear (elem off = t*8 / 2048 + t*8); global source column
    // pre-swizzled: slot_src = (t&3) ^ (row&3).
    const int srow = tid >> 2;
    const int scol = (((tid & 3) ^ (srow & 3)) << 3);
    const uint16_t* gA = A  + (size_t)(mtile * BM8 + srow) * K2 + scol;
    const uint16_t* gB = Bt + (size_t)(ntile * BN8 + srow) * K2 + scol;

#define ST8(b, t) do { \
    gload16(gA + (t) * BK8,                    &As[b][wv * 512]); \
    gload16(gA + (size_t)64 * K2 + (t) * BK8,  &As[b][2048 + wv * 512]); \
    gload16(gB + (t) * BK8,                    &Bs[b][wv * 512]); \
    gload16(gB + (size_t)64 * K2 + (t) * BK8,  &Bs[b][2048 + wv * 512]); } while (0)

    // Fragment reads: row = base + frag*16 + (lane&15); wanted slot = lane>>4;
    // swizzled slot' = (lane>>4) ^ (row&3), row&3 == lane&3.
    // Bank check: 16-lane group covers 8 distinct bank-quads x2 -> free.
    const int fswz = (((lane >> 4) ^ (lane & 3)) << 3);
    const int aoff = (wr * 64 + (lane & 15)) * BK8 + fswz;
    const int boff = (wc * 64 + (lane & 15)) * BK8 + fswz;

    f32x4 acc[4][4];
#pragma unroll
    for (int m = 0; m < 4; m++)
#pragma unroll
        for (int n = 0; n < 4; n++) acc[m][n] = (f32x4){0.f, 0.f, 0.f, 0.f};

    ST8(0, 0);
    __syncthreads();

#pragma unroll 2
    for (int t = 0; t < KT8; ++t) {
        const int b = t & 1;
        if (t + 1 < KT8) ST8(b ^ 1, t + 1);

        bf16x8 af[4], bv[4];
#pragma unroll
        for (int m = 0; m < 4; ++m) af[m] = *(const bf16x8*)&As[b][aoff + m * 16 * BK8];
#pragma unroll
        for (int n = 0; n < 4; ++n) bv[n] = *(const bf16x8*)&Bs[b][boff + n * 16 * BK8];
#pragma unroll
        for (int m = 0; m < 4; ++m)
#pragma unroll
            for (int n = 0; n < 4; ++n)
                acc[m][n] = __builtin_amdgcn_mfma_f32_16x16x32_bf16(af[m], bv[n], acc[m][n], 0, 0, 0);

        __syncthreads();   // compiler drains vmcnt/lgkm here; next tile ready
    }
#undef ST8

    // ---- epilogue: C layout col=lane&15, row=(lane>>4)*4+r (validated) ----
    const int crow0 = (int)mtile * BM8 + wr * 64 + ((lane >> 4) << 2);
    const int ccol0 = (int)ntile * BN8 + wc * 64 + (lane & 15);
#pragma unroll
    for (int m = 0; m < 4; ++m)
#pragma unroll
        for (int n = 0; n < 4; ++n) {
            float* cp = C + (size_t)(crow0 + m * 16) * NOUT + ccol0 + n * 16;
#pragma unroll
            for (int r = 0; r < 4; ++r) cp[(size_t)r * NOUT] = acc[m][n][r];
        }
}

// ---------- launcher ----------
extern "C" void kernel_launch(void* const* d_in, const int* in_sizes, int n_in,
                              void* d_out, int out_size, void* d_ws, size_t ws_size,
                              hipStream_t stream) {
    const float* x    = (const float*)d_in[0];
    const float* lnw  = (const float*)d_in[1];
    const float* lnb  = (const float*)d_in[2];
    const float* bw1  = (const float*)d_in[3];
    const float* sw1  = (const float*)d_in[4];
    const float* ss1  = (const float*)d_in[5];
    const float* bw2  = (const float*)d_in[6];
    const float* sw2  = (const float*)d_in[7];
    const float* ss2  = (const float*)d_in[8];

    char* ws = (char*)d_ws;
    uint16_t* w1L = (uint16_t*)ws;                          // 36,864 B
    uint16_t* w2p = (uint16_t*)(ws + 65536);                // 2,359,296 B
    uint16_t* a2  = (uint16_t*)(ws + 65536 + 2359296);      // 75,497,472 B
    float* out = (float*)d_out;

    pack_w1<<<dim3(72), dim3(256), 0, stream>>>(bw1, sw1, ss1, w1L);
    pack_w2<<<dim3((NOUT * K2 + 255) / 256), dim3(256), 0, stream>>>(bw2, sw2, ss2, w2p);
    featurize<<<dim3(BATCH / FBR), dim3(256), 0, stream>>>(x, lnw, lnb, w1L, a2);
    gemm2_kernel<<<dim3((BATCH / BM8) * (NOUT / BN8)), dim3(256), 0, stream>>>(a2, w2p, out);
}